// Round 14
// baseline (343.839 us; speedup 1.0000x reference)
//
#include <hip/hip_runtime.h>
#include <math.h>

#define DCH 64
#define TD 192      // 3*D
#define RR 20
#define FCUT 5.0f
#define HIST_BLOCKS 512

typedef __attribute__((ext_vector_type(8))) short short8;   // 8 bf16
typedef __attribute__((ext_vector_type(4))) float f32x4;
typedef __attribute__((ext_vector_type(2))) unsigned int u32x2;

__device__ __forceinline__ unsigned short f2bf(float f) {   // f32 -> bf16 RNE
    unsigned int u = __float_as_uint(f);
    u += 0x7FFFu + ((u >> 16) & 1u);
    return (unsigned short)(u >> 16);
}
__device__ __forceinline__ float bflo(unsigned int u) {     // low bf16 -> f32
    return __uint_as_float(u << 16);
}
__device__ __forceinline__ float bfhi(unsigned int u) {     // high bf16 -> f32
    return __uint_as_float(u & 0xFFFF0000u);
}

// -------- Kernel A: fused {edge histogram | MFMA MLP} by block role --------
__global__ __launch_bounds__(256) void mlp_hist_kernel(
    const float* __restrict__ se,
    const float* __restrict__ W1, const float* __restrict__ b1,
    const float* __restrict__ W2, const float* __restrict__ b2,
    unsigned short* __restrict__ h2, int N,
    const int* __restrict__ neigh, int* __restrict__ counts,
    int* __restrict__ pos, int E)
{
    if (blockIdx.x < HIST_BLOCKS) {
        int stride = HIST_BLOCKS * 256;
        for (int e = blockIdx.x * 256 + threadIdx.x; e < E; e += stride) {
            int p = atomicAdd(&counts[neigh[e]], 1);
            pos[e] = p;                         // cached: read by fill soon
        }
        return;
    }

    const int wid  = threadIdx.x >> 6;
    const int lane = threadIdx.x & 63;
    const int g    = lane >> 4;
    const int c    = lane & 15;

    __shared__ float hmid[4][16][68];
    __shared__ unsigned short hstage[4][16][196];

    const int base = (blockIdx.x - HIST_BLOCKS) * 64;
    const int arow = base + wid * 16;
    const int atom = arow + c;
    const bool va  = atom < N;

    const float* sp = se + (size_t)(va ? atom : 0) * DCH;
    short8 A0, A1;
    #pragma unroll
    for (int kh = 0; kh < 2; ++kh) {
        f32x4 q0 = va ? __builtin_nontemporal_load((const f32x4*)(sp + kh*32 + 8*g))
                      : (f32x4){0.f,0.f,0.f,0.f};
        f32x4 q1 = va ? __builtin_nontemporal_load((const f32x4*)(sp + kh*32 + 8*g + 4))
                      : (f32x4){0.f,0.f,0.f,0.f};
        short8& A = kh ? A1 : A0;
        A[0] = (short)f2bf(q0[0]); A[1] = (short)f2bf(q0[1]);
        A[2] = (short)f2bf(q0[2]); A[3] = (short)f2bf(q0[3]);
        A[4] = (short)f2bf(q1[0]); A[5] = (short)f2bf(q1[1]);
        A[6] = (short)f2bf(q1[2]); A[7] = (short)f2bf(q1[3]);
    }

    #pragma unroll
    for (int t = 0; t < 4; ++t) {
        short8 w0, w1;
        #pragma unroll
        for (int j = 0; j < 8; ++j) {
            w0[j] = (short)f2bf(W1[(8 * g + j) * DCH + 16 * t + c]);
            w1[j] = (short)f2bf(W1[(32 + 8 * g + j) * DCH + 16 * t + c]);
        }
        f32x4 C = {0.f, 0.f, 0.f, 0.f};
        C = __builtin_amdgcn_mfma_f32_16x16x32_bf16(A0, w0, C, 0, 0, 0);
        C = __builtin_amdgcn_mfma_f32_16x16x32_bf16(A1, w1, C, 0, 0, 0);
        float bb = b1[16 * t + c];
        #pragma unroll
        for (int reg = 0; reg < 4; ++reg) {
            float x = C[reg] + bb;
            float s = x / (1.0f + __expf(-x));
            hmid[wid][4 * g + reg][16 * t + c] = s;
        }
    }
    __syncthreads();

    short8 B0, B1;
    #pragma unroll
    for (int kh = 0; kh < 2; ++kh) {
        const float* hp = &hmid[wid][c][kh * 32 + 8 * g];
        f32x4 q0 = *(const f32x4*)(hp);
        f32x4 q1 = *(const f32x4*)(hp + 4);
        short8& A = kh ? B1 : B0;
        A[0] = (short)f2bf(q0[0]); A[1] = (short)f2bf(q0[1]);
        A[2] = (short)f2bf(q0[2]); A[3] = (short)f2bf(q0[3]);
        A[4] = (short)f2bf(q1[0]); A[5] = (short)f2bf(q1[1]);
        A[6] = (short)f2bf(q1[2]); A[7] = (short)f2bf(q1[3]);
    }

    #pragma unroll
    for (int t = 0; t < 12; ++t) {
        short8 w0, w1;
        #pragma unroll
        for (int j = 0; j < 8; ++j) {
            w0[j] = (short)f2bf(W2[(8 * g + j) * TD + 16 * t + c]);
            w1[j] = (short)f2bf(W2[(32 + 8 * g + j) * TD + 16 * t + c]);
        }
        f32x4 C = {0.f, 0.f, 0.f, 0.f};
        C = __builtin_amdgcn_mfma_f32_16x16x32_bf16(B0, w0, C, 0, 0, 0);
        C = __builtin_amdgcn_mfma_f32_16x16x32_bf16(B1, w1, C, 0, 0, 0);
        float bb = b2[16 * t + c];
        #pragma unroll
        for (int reg = 0; reg < 4; ++reg)
            hstage[wid][4 * g + reg][c * 12 + t] = f2bf(C[reg] + bb);
    }
    __syncthreads();

    if (lane < 48) {
        #pragma unroll
        for (int i = 0; i < 16; ++i) {
            int a2 = arow + i;
            if (a2 < N)
                *(u32x2*)((char*)h2 + (size_t)a2 * 384 + lane * 8) =
                    *(const u32x2*)(&hstage[wid][i][lane * 4]);
        }
    }
}

// ---------------- scan1: block-local exclusive + block totals ---------------
__global__ __launch_bounds__(256) void scan1_kernel(
    const int* __restrict__ counts, int* __restrict__ starts,
    int* __restrict__ bsums, int N)
{
    int tid = threadIdx.x;
    int gid = blockIdx.x * 256 + tid;
    int v = (gid < N) ? counts[gid] : 0;
    int lane = tid & 63, wid = tid >> 6;
    int x = v;
    #pragma unroll
    for (int off = 1; off < 64; off <<= 1) {
        int y = __shfl_up(x, off, 64);
        if (lane >= off) x += y;
    }
    __shared__ int wsum[4];
    if (lane == 63) wsum[wid] = x;
    __syncthreads();
    int add = 0;
    for (int w = 0; w < wid; ++w) add += wsum[w];
    int incl = x + add;
    if (gid < N) starts[gid] = incl - v;
    if (tid == 255) bsums[blockIdx.x] = incl;
}

__global__ __launch_bounds__(512) void scan2_kernel(int* __restrict__ bsums, int M)
{
    int tid = threadIdx.x;
    int v = (tid < M) ? bsums[tid] : 0;
    int lane = tid & 63, wid = tid >> 6;
    int x = v;
    #pragma unroll
    for (int off = 1; off < 64; off <<= 1) {
        int y = __shfl_up(x, off, 64);
        if (lane >= off) x += y;
    }
    __shared__ int wsum[8];
    if (lane == 63) wsum[wid] = x;
    __syncthreads();
    int add = 0;
    for (int w = 0; w < wid; ++w) add += wsum[w];
    int incl = x + add;
    if (tid < M) bsums[tid] = incl - v;
}

// fill: payload via REGULAR (cached) stores -> L2/L3-resident for gather
__global__ void fill_kernel(const float* __restrict__ nv, const int* __restrict__ central,
                            const int* __restrict__ neigh, const int* __restrict__ starts,
                            const int* __restrict__ bsums, const int* __restrict__ pos,
                            f32x4* __restrict__ payload, int E)
{
    int stride = gridDim.x * blockDim.x;
    for (int e = blockIdx.x * blockDim.x + threadIdx.x; e < E; e += stride) {
        int na = neigh[e];
        int slot = starts[na] + bsums[na >> 8] + pos[e];
        f32x4 pay;
        pay[0] = __builtin_nontemporal_load(&nv[(size_t)e*3+0]);
        pay[1] = __builtin_nontemporal_load(&nv[(size_t)e*3+1]);
        pay[2] = __builtin_nontemporal_load(&nv[(size_t)e*3+2]);
        pay[3] = __int_as_float(central[e]);
        payload[slot] = pay;
    }
}

// ---------------- Kernel C: per-atom gather, MFMA filter --------------------
__global__ __launch_bounds__(256) void gather_kernel(
    const f32x4* __restrict__ payload, const int* __restrict__ starts,
    const int* __restrict__ bsums, const int* __restrict__ counts,
    const unsigned short* __restrict__ h2,
    const float* __restrict__ ve, const float* __restrict__ Wf,
    const float* __restrict__ bfil,
    float* __restrict__ dv, float* __restrict__ ds, int N)
{
    const int wid  = threadIdx.x >> 6;
    const int lane = threadIdx.x & 63;
    const int g    = lane >> 4;
    const int c    = lane & 15;

    short8 Bf[12];
    float  bft[12];
    #pragma unroll
    for (int t = 0; t < 12; ++t) {
        #pragma unroll
        for (int j = 0; j < 8; ++j) {
            int r = 8 * g + j;
            float w = (r < RR) ? Wf[r * TD + 16 * t + c] : 0.0f;
            Bf[t][j] = (short)f2bf(w);
        }
        bft[t] = bfil[16 * t + c];
    }

    const float BC = sqrtf(2.0f / FCUT);
    const float XK = (float)(M_PI / (double)FCUT);
    const char* hb = (const char*)h2;

    for (int atom = blockIdx.x * 4 + wid; atom < N; atom += gridDim.x * 4) {
        const int s   = starts[atom] + bsums[atom >> 8];
        const int cnt = counts[atom];

        float dsa[4] = {0,0,0,0};
        float csm[4] = {0,0,0,0};
        float dvx[4] = {0,0,0,0};
        float dvy[4] = {0,0,0,0};
        float dvz[4] = {0,0,0,0};

        for (int i0 = 0; i0 < cnt; i0 += 16) {
            const bool valid = (i0 + c) < cnt;
            f32x4 p = valid ? payload[s + i0 + c]
                            : (f32x4){1.0f, 0.0f, 0.0f, 0.0f};
            float dist = sqrtf(p[0]*p[0] + p[1]*p[1] + p[2]*p[2]);
            float inv  = 1.0f / dist;
            float xa   = dist * XK;

            float u  = dist * (1.0f / FCUT);
            float u2 = u * u;
            float u6 = u2 * u2 * u2;
            float env = 1.0f + u6 * (-28.0f + u * (48.0f - 21.0f * u));
            env = (dist < FCUT && valid) ? env : 0.0f;
            float scale = BC * inv * env;

            float ux = p[0] * inv, uy = p[1] * inv, uz = p[2] * inv;
            int   ca  = valid ? __float_as_int(p[3]) : 0;
            int   hof = ca * 384;                       // byte offset into h2

            float bas[8];
            bas[0] = __sinf((float)(8 * g + 1) * xa);
            bas[1] = __sinf((float)(8 * g + 2) * xa);
            float twoc = 2.0f * __cosf(xa);
            #pragma unroll
            for (int j = 2; j < 8; ++j)
                bas[j] = fmaf(twoc, bas[j-1], -bas[j-2]);

            short8 A;
            #pragma unroll
            for (int j = 0; j < 8; ++j)
                A[j] = (short)f2bf(bas[j] * scale);

            float env_r[4], ux_r[4], uy_r[4], uz_r[4];
            int   hof_r[4];
            #pragma unroll
            for (int reg = 0; reg < 4; ++reg) {
                int src = 4 * g + reg;
                env_r[reg] = __shfl(env, src, 64);
                ux_r[reg]  = __shfl(ux,  src, 64);
                uy_r[reg]  = __shfl(uy,  src, 64);
                uz_r[reg]  = __shfl(uz,  src, 64);
                hof_r[reg] = __shfl(hof, src, 64);
            }

            // issue the 12 h row-loads early (cached; latency hides under MFMA)
            u32x2 hq[4][3];
            #pragma unroll
            for (int reg = 0; reg < 4; ++reg) {
                const char* rp = hb + (size_t)(unsigned)hof_r[reg] + c * 24;
                hq[reg][0] = *(const u32x2*)(rp);
                hq[reg][1] = *(const u32x2*)(rp + 8);
                hq[reg][2] = *(const u32x2*)(rp + 16);
            }

            #pragma unroll
            for (int t = 0; t < 12; ++t) {
                f32x4 C = __builtin_amdgcn_mfma_f32_16x16x32_bf16(
                    A, Bf[t], (f32x4){0.f,0.f,0.f,0.f}, 0, 0, 0);
                #pragma unroll
                for (int reg = 0; reg < 4; ++reg) {
                    unsigned int w = hq[reg][t >> 2][(t >> 1) & 1];
                    float hv = (t & 1) ? bfhi(w) : bflo(w);
                    float filt = fmaf(bft[t], env_r[reg], C[reg]);
                    if (t < 4) {
                        dsa[t] = fmaf(filt, hv, dsa[t]);
                    } else if (t < 8) {
                        float bh = filt * hv;
                        dvx[t-4] = fmaf(bh, ux_r[reg], dvx[t-4]);
                        dvy[t-4] = fmaf(bh, uy_r[reg], dvy[t-4]);
                        dvz[t-4] = fmaf(bh, uz_r[reg], dvz[t-4]);
                    } else {
                        csm[t-8] = fmaf(filt, hv, csm[t-8]);
                    }
                }
            }
        }

        // ---- epilogue: ve loads issued FIRST (hide under reduction shfls) ----
        int ch = 16 * g + c;
        size_t vb = (size_t)atom * TD + (size_t)ch * 3;
        float v0 = __builtin_nontemporal_load(&ve[vb + 0]);
        float v1 = __builtin_nontemporal_load(&ve[vb + 1]);
        float v2 = __builtin_nontemporal_load(&ve[vb + 2]);

        // 3-shfl transpose-reduce: lane (g,c) gets full sum of its tile t=g
        auto sel4 = [](const float* v, int k) {
            return (k == 0) ? v[0] : (k == 1) ? v[1] : (k == 2) ? v[2] : v[3];
        };
        auto red4 = [&](const float* v) {
            float a = sel4(v, g)     + __shfl_xor(sel4(v, g ^ 1), 16, 64);
            float b = sel4(v, g ^ 2) + __shfl_xor(sel4(v, g ^ 3), 16, 64);
            return a + __shfl_xor(b, 32, 64);
        };
        float dssel = red4(dsa);
        float cssel = red4(csm);
        float vxsel = red4(dvx);
        float vysel = red4(dvy);
        float vzsel = red4(dvz);

        __builtin_nontemporal_store(fmaf(cssel, v0, vxsel), &dv[vb + 0]);
        __builtin_nontemporal_store(fmaf(cssel, v1, vysel), &dv[vb + 1]);
        __builtin_nontemporal_store(fmaf(cssel, v2, vzsel), &dv[vb + 2]);
        __builtin_nontemporal_store(dssel, &ds[(size_t)atom * DCH + ch]);
    }
}

extern "C" void kernel_launch(void* const* d_in, const int* in_sizes, int n_in,
                              void* d_out, int out_size, void* d_ws, size_t ws_size,
                              hipStream_t stream) {
    const float* ve      = (const float*)d_in[0];
    const float* se      = (const float*)d_in[1];
    const float* nv      = (const float*)d_in[2];
    const int*   central = (const int*)  d_in[3];
    const int*   neigh   = (const int*)  d_in[4];
    const float* Wf      = (const float*)d_in[6];
    const float* bfil    = (const float*)d_in[7];
    const float* W1      = (const float*)d_in[8];
    const float* b1      = (const float*)d_in[9];
    const float* W2      = (const float*)d_in[10];
    const float* b2      = (const float*)d_in[11];

    const int N = in_sizes[1] / DCH;
    const int E = in_sizes[3];

    float* out = (float*)d_out;
    float* dv  = out;
    float* ds  = out + (size_t)N * TD;

    char* wsb = (char*)d_ws;
    size_t off = 0;
    auto wsalloc = [&](size_t bytes) -> void* {
        void* p = wsb + off;
        off = (off + bytes + 255) & ~(size_t)255;
        return p;
    };
    unsigned short* h2      = (unsigned short*)wsalloc((size_t)N * 192 * 2);
    int*            counts  = (int*)   wsalloc((size_t)N * 4);
    int*            starts  = (int*)   wsalloc((size_t)N * 4);
    int*            pos     = (int*)   wsalloc((size_t)E * 4);
    f32x4*          payload = (f32x4*) wsalloc((size_t)E * 16);
    int*            bsums   = (int*)   wsalloc(4096);

    const int nb1 = (N + 255) / 256;
    const int nbm = (N + 63) / 64;

    hipMemsetAsync(counts, 0, (size_t)N * 4, stream);
    mlp_hist_kernel<<<HIST_BLOCKS + nbm, 256, 0, stream>>>(
        se, W1, b1, W2, b2, h2, N, neigh, counts, pos, E);
    scan1_kernel<<<nb1, 256, 0, stream>>>(counts, starts, bsums, N);
    scan2_kernel<<<1, 512, 0, stream>>>(bsums, nb1);
    fill_kernel<<<2048, 256, 0, stream>>>(nv, central, neigh, starts, bsums, pos,
                                          payload, E);
    gather_kernel<<<2048, 256, 0, stream>>>(payload, starts, bsums, counts, h2, ve,
                                            Wf, bfil, dv, ds, N);
}

// Round 15
// 322.198 us; speedup vs baseline: 1.0672x; 1.0672x over previous
//
#include <hip/hip_runtime.h>
#include <math.h>

#define DCH 64
#define TD 192      // 3*D
#define RR 20
#define FCUT 5.0f
#define HIST_BLOCKS 512

typedef __attribute__((ext_vector_type(8))) short short8;   // 8 bf16
typedef __attribute__((ext_vector_type(4))) float f32x4;
typedef __attribute__((ext_vector_type(2))) unsigned int u32x2;

__device__ __forceinline__ unsigned short f2bf(float f) {   // f32 -> bf16 RNE
    unsigned int u = __float_as_uint(f);
    u += 0x7FFFu + ((u >> 16) & 1u);
    return (unsigned short)(u >> 16);
}
__device__ __forceinline__ float bflo(unsigned int u) {     // low bf16 -> f32
    return __uint_as_float(u << 16);
}
__device__ __forceinline__ float bfhi(unsigned int u) {     // high bf16 -> f32
    return __uint_as_float(u & 0xFFFF0000u);
}

// -------- Kernel A: fused {edge histogram | MFMA MLP} by block role --------
__global__ __launch_bounds__(256) void mlp_hist_kernel(
    const float* __restrict__ se,
    const float* __restrict__ W1, const float* __restrict__ b1,
    const float* __restrict__ W2, const float* __restrict__ b2,
    unsigned short* __restrict__ h2, int N,
    const int* __restrict__ neigh, int* __restrict__ counts,
    int* __restrict__ pos, int E)
{
    if (blockIdx.x < HIST_BLOCKS) {
        int stride = HIST_BLOCKS * 256;
        for (int e = blockIdx.x * 256 + threadIdx.x; e < E; e += stride) {
            int p = atomicAdd(&counts[neigh[e]], 1);
            pos[e] = p;                         // cached: read by fill soon
        }
        return;
    }

    const int wid  = threadIdx.x >> 6;
    const int lane = threadIdx.x & 63;
    const int g    = lane >> 4;
    const int c    = lane & 15;

    __shared__ float hmid[4][16][68];
    __shared__ unsigned short hstage[4][16][196];

    const int base = (blockIdx.x - HIST_BLOCKS) * 64;
    const int arow = base + wid * 16;
    const int atom = arow + c;
    const bool va  = atom < N;

    const float* sp = se + (size_t)(va ? atom : 0) * DCH;
    short8 A0, A1;
    #pragma unroll
    for (int kh = 0; kh < 2; ++kh) {
        f32x4 q0 = va ? __builtin_nontemporal_load((const f32x4*)(sp + kh*32 + 8*g))
                      : (f32x4){0.f,0.f,0.f,0.f};
        f32x4 q1 = va ? __builtin_nontemporal_load((const f32x4*)(sp + kh*32 + 8*g + 4))
                      : (f32x4){0.f,0.f,0.f,0.f};
        short8& A = kh ? A1 : A0;
        A[0] = (short)f2bf(q0[0]); A[1] = (short)f2bf(q0[1]);
        A[2] = (short)f2bf(q0[2]); A[3] = (short)f2bf(q0[3]);
        A[4] = (short)f2bf(q1[0]); A[5] = (short)f2bf(q1[1]);
        A[6] = (short)f2bf(q1[2]); A[7] = (short)f2bf(q1[3]);
    }

    #pragma unroll
    for (int t = 0; t < 4; ++t) {
        short8 w0, w1;
        #pragma unroll
        for (int j = 0; j < 8; ++j) {
            w0[j] = (short)f2bf(W1[(8 * g + j) * DCH + 16 * t + c]);
            w1[j] = (short)f2bf(W1[(32 + 8 * g + j) * DCH + 16 * t + c]);
        }
        f32x4 C = {0.f, 0.f, 0.f, 0.f};
        C = __builtin_amdgcn_mfma_f32_16x16x32_bf16(A0, w0, C, 0, 0, 0);
        C = __builtin_amdgcn_mfma_f32_16x16x32_bf16(A1, w1, C, 0, 0, 0);
        float bb = b1[16 * t + c];
        #pragma unroll
        for (int reg = 0; reg < 4; ++reg) {
            float x = C[reg] + bb;
            float s = x / (1.0f + __expf(-x));
            hmid[wid][4 * g + reg][16 * t + c] = s;
        }
    }
    __syncthreads();

    short8 B0, B1;
    #pragma unroll
    for (int kh = 0; kh < 2; ++kh) {
        const float* hp = &hmid[wid][c][kh * 32 + 8 * g];
        f32x4 q0 = *(const f32x4*)(hp);
        f32x4 q1 = *(const f32x4*)(hp + 4);
        short8& A = kh ? B1 : B0;
        A[0] = (short)f2bf(q0[0]); A[1] = (short)f2bf(q0[1]);
        A[2] = (short)f2bf(q0[2]); A[3] = (short)f2bf(q0[3]);
        A[4] = (short)f2bf(q1[0]); A[5] = (short)f2bf(q1[1]);
        A[6] = (short)f2bf(q1[2]); A[7] = (short)f2bf(q1[3]);
    }

    #pragma unroll
    for (int t = 0; t < 12; ++t) {
        short8 w0, w1;
        #pragma unroll
        for (int j = 0; j < 8; ++j) {
            w0[j] = (short)f2bf(W2[(8 * g + j) * TD + 16 * t + c]);
            w1[j] = (short)f2bf(W2[(32 + 8 * g + j) * TD + 16 * t + c]);
        }
        f32x4 C = {0.f, 0.f, 0.f, 0.f};
        C = __builtin_amdgcn_mfma_f32_16x16x32_bf16(B0, w0, C, 0, 0, 0);
        C = __builtin_amdgcn_mfma_f32_16x16x32_bf16(B1, w1, C, 0, 0, 0);
        float bb = b2[16 * t + c];
        #pragma unroll
        for (int reg = 0; reg < 4; ++reg)
            hstage[wid][4 * g + reg][c * 12 + t] = f2bf(C[reg] + bb);
    }
    __syncthreads();

    if (lane < 48) {
        #pragma unroll
        for (int i = 0; i < 16; ++i) {
            int a2 = arow + i;
            if (a2 < N)
                *(u32x2*)((char*)h2 + (size_t)a2 * 384 + lane * 8) =
                    *(const u32x2*)(&hstage[wid][i][lane * 4]);
        }
    }
}

// ---------------- scan1: block-local exclusive + block totals ---------------
__global__ __launch_bounds__(256) void scan1_kernel(
    const int* __restrict__ counts, int* __restrict__ starts,
    int* __restrict__ bsums, int N)
{
    int tid = threadIdx.x;
    int gid = blockIdx.x * 256 + tid;
    int v = (gid < N) ? counts[gid] : 0;
    int lane = tid & 63, wid = tid >> 6;
    int x = v;
    #pragma unroll
    for (int off = 1; off < 64; off <<= 1) {
        int y = __shfl_up(x, off, 64);
        if (lane >= off) x += y;
    }
    __shared__ int wsum[4];
    if (lane == 63) wsum[wid] = x;
    __syncthreads();
    int add = 0;
    for (int w = 0; w < wid; ++w) add += wsum[w];
    int incl = x + add;
    if (gid < N) starts[gid] = incl - v;
    if (tid == 255) bsums[blockIdx.x] = incl;
}

__global__ __launch_bounds__(512) void scan2_kernel(int* __restrict__ bsums, int M)
{
    int tid = threadIdx.x;
    int v = (tid < M) ? bsums[tid] : 0;
    int lane = tid & 63, wid = tid >> 6;
    int x = v;
    #pragma unroll
    for (int off = 1; off < 64; off <<= 1) {
        int y = __shfl_up(x, off, 64);
        if (lane >= off) x += y;
    }
    __shared__ int wsum[8];
    if (lane == 63) wsum[wid] = x;
    __syncthreads();
    int add = 0;
    for (int w = 0; w < wid; ++w) add += wsum[w];
    int incl = x + add;
    if (tid < M) bsums[tid] = incl - v;
}

// fill: payload via REGULAR (cached) stores -> L2/L3-resident for gather
__global__ void fill_kernel(const float* __restrict__ nv, const int* __restrict__ central,
                            const int* __restrict__ neigh, const int* __restrict__ starts,
                            const int* __restrict__ bsums, const int* __restrict__ pos,
                            f32x4* __restrict__ payload, int E)
{
    int stride = gridDim.x * blockDim.x;
    for (int e = blockIdx.x * blockDim.x + threadIdx.x; e < E; e += stride) {
        int na = neigh[e];
        int slot = starts[na] + bsums[na >> 8] + pos[e];
        f32x4 pay;
        pay[0] = __builtin_nontemporal_load(&nv[(size_t)e*3+0]);
        pay[1] = __builtin_nontemporal_load(&nv[(size_t)e*3+1]);
        pay[2] = __builtin_nontemporal_load(&nv[(size_t)e*3+2]);
        pay[3] = __int_as_float(central[e]);
        payload[slot] = pay;
    }
}

// ---------------- Kernel C: per-atom gather, MFMA filter (R13 form) ---------
__global__ __launch_bounds__(256) void gather_kernel(
    const f32x4* __restrict__ payload, const int* __restrict__ starts,
    const int* __restrict__ bsums, const int* __restrict__ counts,
    const unsigned short* __restrict__ h2,
    const float* __restrict__ ve, const float* __restrict__ Wf,
    const float* __restrict__ bfil,
    float* __restrict__ dv, float* __restrict__ ds, int N)
{
    const int wid  = threadIdx.x >> 6;
    const int lane = threadIdx.x & 63;
    const int g    = lane >> 4;
    const int c    = lane & 15;

    short8 Bf[12];
    float  bft[12];
    #pragma unroll
    for (int t = 0; t < 12; ++t) {
        #pragma unroll
        for (int j = 0; j < 8; ++j) {
            int r = 8 * g + j;
            float w = (r < RR) ? Wf[r * TD + 16 * t + c] : 0.0f;
            Bf[t][j] = (short)f2bf(w);
        }
        bft[t] = bfil[16 * t + c];
    }

    const float BC = sqrtf(2.0f / FCUT);
    const float XK = (float)(M_PI / (double)FCUT);
    const char* hb = (const char*)h2;

    for (int atom = blockIdx.x * 4 + wid; atom < N; atom += gridDim.x * 4) {
        const int s   = starts[atom] + bsums[atom >> 8];
        const int cnt = counts[atom];

        float dsa[4] = {0,0,0,0};
        float csm[4] = {0,0,0,0};
        float dvx[4] = {0,0,0,0};
        float dvy[4] = {0,0,0,0};
        float dvz[4] = {0,0,0,0};

        for (int i0 = 0; i0 < cnt; i0 += 16) {
            const bool valid = (i0 + c) < cnt;
            f32x4 p = valid ? payload[s + i0 + c]
                            : (f32x4){1.0f, 0.0f, 0.0f, 0.0f};
            float dist = sqrtf(p[0]*p[0] + p[1]*p[1] + p[2]*p[2]);
            float inv  = 1.0f / dist;
            float xa   = dist * XK;

            float u  = dist * (1.0f / FCUT);
            float u2 = u * u;
            float u6 = u2 * u2 * u2;
            float env = 1.0f + u6 * (-28.0f + u * (48.0f - 21.0f * u));
            env = (dist < FCUT && valid) ? env : 0.0f;
            float scale = BC * inv * env;

            float ux = p[0] * inv, uy = p[1] * inv, uz = p[2] * inv;
            int   ca  = valid ? __float_as_int(p[3]) : 0;
            int   hof = ca * 384;                       // byte offset into h2

            float bas[8];
            bas[0] = __sinf((float)(8 * g + 1) * xa);
            bas[1] = __sinf((float)(8 * g + 2) * xa);
            float twoc = 2.0f * __cosf(xa);
            #pragma unroll
            for (int j = 2; j < 8; ++j)
                bas[j] = fmaf(twoc, bas[j-1], -bas[j-2]);

            short8 A;
            #pragma unroll
            for (int j = 0; j < 8; ++j)
                A[j] = (short)f2bf(bas[j] * scale);

            float env_r[4], ux_r[4], uy_r[4], uz_r[4];
            int   hof_r[4];
            #pragma unroll
            for (int reg = 0; reg < 4; ++reg) {
                int src = 4 * g + reg;
                env_r[reg] = __shfl(env, src, 64);
                ux_r[reg]  = __shfl(ux,  src, 64);
                uy_r[reg]  = __shfl(uy,  src, 64);
                uz_r[reg]  = __shfl(uz,  src, 64);
                hof_r[reg] = __shfl(hof, src, 64);
            }

            // issue the 12 h row-loads early (cached; latency hides under MFMA)
            u32x2 hq[4][3];
            #pragma unroll
            for (int reg = 0; reg < 4; ++reg) {
                const char* rp = hb + (size_t)(unsigned)hof_r[reg] + c * 24;
                hq[reg][0] = *(const u32x2*)(rp);
                hq[reg][1] = *(const u32x2*)(rp + 8);
                hq[reg][2] = *(const u32x2*)(rp + 16);
            }

            #pragma unroll
            for (int t = 0; t < 12; ++t) {
                f32x4 C = __builtin_amdgcn_mfma_f32_16x16x32_bf16(
                    A, Bf[t], (f32x4){0.f,0.f,0.f,0.f}, 0, 0, 0);
                #pragma unroll
                for (int reg = 0; reg < 4; ++reg) {
                    unsigned int w = hq[reg][t >> 2][(t >> 1) & 1];
                    float hv = (t & 1) ? bfhi(w) : bflo(w);
                    float filt = fmaf(bft[t], env_r[reg], C[reg]);
                    if (t < 4) {
                        dsa[t] = fmaf(filt, hv, dsa[t]);
                    } else if (t < 8) {
                        float bh = filt * hv;
                        dvx[t-4] = fmaf(bh, ux_r[reg], dvx[t-4]);
                        dvy[t-4] = fmaf(bh, uy_r[reg], dvy[t-4]);
                        dvz[t-4] = fmaf(bh, uz_r[reg], dvz[t-4]);
                    } else {
                        csm[t-8] = fmaf(filt, hv, csm[t-8]);
                    }
                }
            }
        }

        #pragma unroll
        for (int t = 0; t < 4; ++t) {
            dsa[t] += __shfl_xor(dsa[t], 16, 64); dsa[t] += __shfl_xor(dsa[t], 32, 64);
            csm[t] += __shfl_xor(csm[t], 16, 64); csm[t] += __shfl_xor(csm[t], 32, 64);
            dvx[t] += __shfl_xor(dvx[t], 16, 64); dvx[t] += __shfl_xor(dvx[t], 32, 64);
            dvy[t] += __shfl_xor(dvy[t], 16, 64); dvy[t] += __shfl_xor(dvy[t], 32, 64);
            dvz[t] += __shfl_xor(dvz[t], 16, 64); dvz[t] += __shfl_xor(dvz[t], 32, 64);
        }

        float dssel = (g==0) ? dsa[0] : (g==1) ? dsa[1] : (g==2) ? dsa[2] : dsa[3];
        float cssel = (g==0) ? csm[0] : (g==1) ? csm[1] : (g==2) ? csm[2] : csm[3];
        float vxsel = (g==0) ? dvx[0] : (g==1) ? dvx[1] : (g==2) ? dvx[2] : dvx[3];
        float vysel = (g==0) ? dvy[0] : (g==1) ? dvy[1] : (g==2) ? dvy[2] : dvy[3];
        float vzsel = (g==0) ? dvz[0] : (g==1) ? dvz[1] : (g==2) ? dvz[2] : dvz[3];

        int ch = 16 * g + c;
        size_t vb = (size_t)atom * TD + (size_t)ch * 3;
        float v0 = __builtin_nontemporal_load(&ve[vb + 0]);
        float v1 = __builtin_nontemporal_load(&ve[vb + 1]);
        float v2 = __builtin_nontemporal_load(&ve[vb + 2]);
        __builtin_nontemporal_store(fmaf(cssel, v0, vxsel), &dv[vb + 0]);
        __builtin_nontemporal_store(fmaf(cssel, v1, vysel), &dv[vb + 1]);
        __builtin_nontemporal_store(fmaf(cssel, v2, vzsel), &dv[vb + 2]);
        __builtin_nontemporal_store(dssel, &ds[(size_t)atom * DCH + ch]);
    }
}

extern "C" void kernel_launch(void* const* d_in, const int* in_sizes, int n_in,
                              void* d_out, int out_size, void* d_ws, size_t ws_size,
                              hipStream_t stream) {
    const float* ve      = (const float*)d_in[0];
    const float* se      = (const float*)d_in[1];
    const float* nv      = (const float*)d_in[2];
    const int*   central = (const int*)  d_in[3];
    const int*   neigh   = (const int*)  d_in[4];
    const float* Wf      = (const float*)d_in[6];
    const float* bfil    = (const float*)d_in[7];
    const float* W1      = (const float*)d_in[8];
    const float* b1      = (const float*)d_in[9];
    const float* W2      = (const float*)d_in[10];
    const float* b2      = (const float*)d_in[11];

    const int N = in_sizes[1] / DCH;
    const int E = in_sizes[3];

    float* out = (float*)d_out;
    float* dv  = out;
    float* ds  = out + (size_t)N * TD;

    char* wsb = (char*)d_ws;
    size_t off = 0;
    auto wsalloc = [&](size_t bytes) -> void* {
        void* p = wsb + off;
        off = (off + bytes + 255) & ~(size_t)255;
        return p;
    };
    unsigned short* h2      = (unsigned short*)wsalloc((size_t)N * 192 * 2);
    int*            counts  = (int*)   wsalloc((size_t)N * 4);
    int*            starts  = (int*)   wsalloc((size_t)N * 4);
    int*            pos     = (int*)   wsalloc((size_t)E * 4);
    f32x4*          payload = (f32x4*) wsalloc((size_t)E * 16);
    int*            bsums   = (int*)   wsalloc(4096);

    const int nb1 = (N + 255) / 256;
    const int nbm = (N + 63) / 64;

    hipMemsetAsync(counts, 0, (size_t)N * 4, stream);
    mlp_hist_kernel<<<HIST_BLOCKS + nbm, 256, 0, stream>>>(
        se, W1, b1, W2, b2, h2, N, neigh, counts, pos, E);
    scan1_kernel<<<nb1, 256, 0, stream>>>(counts, starts, bsums, N);
    scan2_kernel<<<1, 512, 0, stream>>>(bsums, nb1);
    fill_kernel<<<2048, 256, 0, stream>>>(nv, central, neigh, starts, bsums, pos,
                                          payload, E);
    gather_kernel<<<2048, 256, 0, stream>>>(payload, starts, bsums, counts, h2, ve,
                                            Wf, bfil, dv, ds, N);
}